// Round 5
// baseline (257.297 us; speedup 1.0000x reference)
//
#include <hip/hip_runtime.h>
#include <hip/hip_bf16.h>
#include <math.h>

// Problem constants: B=64, L=256, H=64
#define PB 64
#define PL 256
#define PH 64
#define TEMP 0.07f
#define NEG_INF_F (-1e9f)

#define KSTRIDE 72   // bf16 elements per staged K row (64 + 8 pad)

typedef short short8 __attribute__((ext_vector_type(8)));   // 8 bf16 (4 VGPRs)
typedef float f32x4 __attribute__((ext_vector_type(4)));

// fp32 pair -> packed bf16x2 (RTNE)
__device__ __forceinline__ unsigned int pkbf(float a, float b) {
    __hip_bfloat162 h = __float22bfloat162_rn(float2{a, b});
    union { __hip_bfloat162 h2; unsigned int u; } cvt;
    cvt.h2 = h;
    return cvt.u;
}

// Max over all 16 lanes of each DPP row, via rotate-and-max doubling (VALU pipe,
// not DS pipe: this replaces ds_swizzle-based __shfl_xor).
__device__ __forceinline__ float rowmax16(float v) {
    int x;
    x = __builtin_amdgcn_update_dpp(0, __float_as_int(v), 0x121, 0xf, 0xf, true); // row_ror:1
    v = fmaxf(v, __int_as_float(x));
    x = __builtin_amdgcn_update_dpp(0, __float_as_int(v), 0x122, 0xf, 0xf, true); // row_ror:2
    v = fmaxf(v, __int_as_float(x));
    x = __builtin_amdgcn_update_dpp(0, __float_as_int(v), 0x124, 0xf, 0xf, true); // row_ror:4
    v = fmaxf(v, __int_as_float(x));
    x = __builtin_amdgcn_update_dpp(0, __float_as_int(v), 0x128, 0xf, 0xf, true); // row_ror:8
    v = fmaxf(v, __int_as_float(x));
    return v;
}

// Sum over all 16 lanes of each DPP row (rotate-and-add doubling).
__device__ __forceinline__ float rowsum16(float v) {
    int x;
    x = __builtin_amdgcn_update_dpp(0, __float_as_int(v), 0x121, 0xf, 0xf, true);
    v += __int_as_float(x);
    x = __builtin_amdgcn_update_dpp(0, __float_as_int(v), 0x122, 0xf, 0xf, true);
    v += __int_as_float(x);
    x = __builtin_amdgcn_update_dpp(0, __float_as_int(v), 0x124, 0xf, 0xf, true);
    v += __int_as_float(x);
    x = __builtin_amdgcn_update_dpp(0, __float_as_int(v), 0x128, 0xf, 0xf, true);
    v += __int_as_float(x);
    return v;
}

// ---------------- fp32 -> bf16 convert ----------------
__global__ void convert_kernel(const float* __restrict__ Q,
                               const float* __restrict__ K,
                               unsigned short* __restrict__ Qb,
                               unsigned short* __restrict__ Kb) {
    const int t = blockIdx.x * blockDim.x + threadIdx.x;
    const int NV4 = (PB * PL * PH) / 4;   // 262144 float4 per tensor
    const float4* src;
    unsigned short* dst;
    int i;
    if (t < NV4) { src = (const float4*)Q; dst = Qb; i = t; }
    else         { src = (const float4*)K; dst = Kb; i = t - NV4; }
    float4 v = src[i];
    uint2 o;
    o.x = pkbf(v.x, v.y);
    o.y = pkbf(v.z, v.w);
    *(uint2*)(dst + (size_t)i * 4) = o;
}

// ---------------- main scores kernel: one block per (b,c) ----------------
// 4 waves: wave w handles rows (w&1)*128..+127 (8 row-tiles) and
// col-tiles (w>>1)*8..+7 (128 k-cols). Wave pairs (0,2) and (1,3) cover the
// same rows with disjoint col-tiles; their maxes combine through LDS.
__global__ __launch_bounds__(256, 3)
void colbert_scores_mfma(const unsigned short* __restrict__ Qb,
                         const unsigned short* __restrict__ Kb,
                         const int*   __restrict__ qmask,
                         const int*   __restrict__ kmask,
                         float*       __restrict__ scores) {
    const int c = blockIdx.x;
    const int b = blockIdx.y;
    const int tid  = threadIdx.x;
    const int wave = tid >> 6;
    const int lane = tid & 63;
    const int n    = lane & 15;        // col / row-within-tile index
    const int g    = (lane >> 4) & 3;  // quad index

    __shared__ __align__(16) unsigned short Ks[PL * KSTRIDE];  // 36 KB
    __shared__ float qmF[PL];
    __shared__ __align__(16) float redbuf[2][PL];              // per-pair row maxes
    __shared__ float red4[4];

    // Stage qmask as float.
    qmF[tid] = (float)qmask[b * PL + tid];

    // Stage K_c (256 x 64 bf16) into LDS, padded stride.
    {
        const unsigned short* Kbase = Kb + (size_t)c * PL * PH;
        #pragma unroll
        for (int it = 0; it < 8; ++it) {
            int lin = it * 256 + tid;          // 16B chunk index, 2048 total
            int row = lin >> 3;
            int off = lin & 7;
            short8 v = *(const short8*)(Kbase + (size_t)row * PH + off * 8);
            *(short8*)(&Ks[row * KSTRIDE + off * 8]) = v;
        }
    }

    const int rowbase = (wave & 1) * 128;   // this wave's 128 q-rows
    const int ctbase  = (wave >> 1) * 8;    // this wave's 8 col-tiles
    const int pair    = wave >> 1;

    // Per-lane key-mask bias for this wave's col-tiles.
    float biasv[8];
    #pragma unroll
    for (int j = 0; j < 8; ++j)
        biasv[j] = kmask[c * PL + (ctbase + j) * 16 + n] ? 0.0f : NEG_INF_F;

    // A-fragments for 8 row-tiles (global bf16, independent loads).
    short8 afrag[8][2];
    {
        const unsigned short* Qrow = Qb + (size_t)b * PL * PH;
        #pragma unroll
        for (int rt = 0; rt < 8; ++rt) {
            const unsigned short* p = Qrow + (size_t)(rowbase + rt * 16 + n) * PH + g * 8;
            afrag[rt][0] = *(const short8*)(p);
            afrag[rt][1] = *(const short8*)(p + 32);
        }
    }

    __syncthreads();   // Ks + qmF visible

    // Running masked max per (rt, r).
    float maxv[8][4];
    #pragma unroll
    for (int rt = 0; rt < 8; ++rt)
        #pragma unroll
        for (int r = 0; r < 4; ++r) maxv[rt][r] = NEG_INF_F;

    const unsigned short* krow0 = &Ks[n * KSTRIDE + g * 8];
    #pragma unroll
    for (int j = 0; j < 8; ++j) {
        const int ct = ctbase + j;
        short8 kb0 = *(const short8*)(krow0 + ct * 16 * KSTRIDE);
        short8 kb1 = *(const short8*)(krow0 + ct * 16 * KSTRIDE + 32);
        const float bias = biasv[j];
        const f32x4 bias4 = {bias, bias, bias, bias};

        f32x4 acc[8];
        #pragma unroll
        for (int rt = 0; rt < 8; ++rt)
            acc[rt] = __builtin_amdgcn_mfma_f32_16x16x32_bf16(afrag[rt][0], kb0, bias4, 0, 0, 0);
        #pragma unroll
        for (int rt = 0; rt < 8; ++rt)
            acc[rt] = __builtin_amdgcn_mfma_f32_16x16x32_bf16(afrag[rt][1], kb1, acc[rt], 0, 0, 0);

        #pragma unroll
        for (int rt = 0; rt < 8; ++rt)
            #pragma unroll
            for (int r = 0; r < 4; ++r)
                maxv[rt][r] = fmaxf(maxv[rt][r], acc[rt][r]);
    }

    // 16-lane (col) max via DPP; n==0 lanes write packed row maxes to LDS.
    #pragma unroll
    for (int rt = 0; rt < 8; ++rt) {
        f32x4 m4;
        m4[0] = rowmax16(maxv[rt][0]);
        m4[1] = rowmax16(maxv[rt][1]);
        m4[2] = rowmax16(maxv[rt][2]);
        m4[3] = rowmax16(maxv[rt][3]);
        if (n == 0)
            *(f32x4*)(&redbuf[pair][rowbase + rt * 16 + g * 4]) = m4;
    }

    __syncthreads();   // redbuf complete

    // Combine pairs, weight by qmask, block-sum. tid = row.
    {
        float m = fmaxf(redbuf[0][tid], redbuf[1][tid]);
        float val = m * qmF[tid];
        float s = rowsum16(val);                 // 16-lane sums (VALU)
        s += __shfl_xor(s, 16, 64);              // cross-row (DS, 2 ops, once)
        s += __shfl_xor(s, 32, 64);
        if (lane == 0) red4[wave] = s;
    }
    __syncthreads();
    if (tid == 0)
        scores[b * PB + c] = (red4[0] + red4[1] + red4[2] + red4[3]) * (1.0f / TEMP);
}

// ---------------- finalize: log-softmax CE ----------------
__global__ void finalize_kernel(const float* __restrict__ scores,
                                const int*   __restrict__ labels,
                                float*       __restrict__ out) {
    const int r = threadIdx.x;   // 64 threads, one per row
    float4 v[16];
    const float4* row4 = (const float4*)(scores + r * PB);
    #pragma unroll
    for (int i = 0; i < 16; ++i) v[i] = row4[i];
    float mx = NEG_INF_F;
    #pragma unroll
    for (int i = 0; i < 16; ++i)
        mx = fmaxf(mx, fmaxf(fmaxf(v[i].x, v[i].y), fmaxf(v[i].z, v[i].w)));
    float se = 0.0f;
    #pragma unroll
    for (int i = 0; i < 16; ++i)
        se += expf(v[i].x - mx) + expf(v[i].y - mx) +
              expf(v[i].z - mx) + expf(v[i].w - mx);
    float diag = ((const float*)v)[r & 63];
    float logp_diag = diag - mx - logf(se);
    float w = (float)labels[r];
    float wd = w * logp_diag;
    #pragma unroll
    for (int off = 32; off >= 1; off >>= 1) {
        wd += __shfl_xor(wd, off, 64);
        w  += __shfl_xor(w,  off, 64);
    }
    if (r == 0) out[0] = -wd / fmaxf(w, 1.0f);
}

extern "C" void kernel_launch(void* const* d_in, const int* in_sizes, int n_in,
                              void* d_out, int out_size, void* d_ws, size_t ws_size,
                              hipStream_t stream) {
    const float* Q      = (const float*)d_in[0];
    const float* K      = (const float*)d_in[1];
    const int*   labels = (const int*)d_in[2];
    const int*   qmask  = (const int*)d_in[3];
    const int*   kmask  = (const int*)d_in[4];
    float*       out    = (float*)d_out;

    // ws layout: [scores 16KB][Qb 2MB][Kb 2MB]
    char* ws = (char*)d_ws;
    float*          scores = (float*)ws;
    unsigned short* Qb     = (unsigned short*)(ws + 16 * 1024);
    unsigned short* Kb     = (unsigned short*)(ws + 16 * 1024 + 2 * 1024 * 1024);

    const int total_v4 = 2 * (PB * PL * PH) / 4;   // 524288
    convert_kernel<<<total_v4 / 256, 256, 0, stream>>>(Q, K, Qb, Kb);

    dim3 grid(PB, PB);   // x = c, y = b; one block per (b,c), no atomics
    colbert_scores_mfma<<<grid, 256, 0, stream>>>(Qb, Kb, qmask, kmask, scores);
    finalize_kernel<<<1, 64, 0, stream>>>(scores, labels, out);
}

// Round 6
// 115.553 us; speedup vs baseline: 2.2266x; 2.2266x over previous
//
#include <hip/hip_runtime.h>
#include <hip/hip_bf16.h>
#include <math.h>

// Problem constants: B=64, L=256, H=64
#define PB 64
#define PL 256
#define PH 64
#define TEMP 0.07f
#define NEG_INF_F (-1e9f)

#define KSTRIDE 72   // bf16 elements per staged K row (64 + 8 pad; 144 B)

typedef short short8 __attribute__((ext_vector_type(8)));   // 8 bf16 (4 VGPRs)
typedef float f32x4 __attribute__((ext_vector_type(4)));

// fp32 pair -> packed bf16x2 (RTNE)
__device__ __forceinline__ unsigned int pkbf(float a, float b) {
    __hip_bfloat162 h = __float22bfloat162_rn(float2{a, b});
    union { __hip_bfloat162 h2; unsigned int u; } cvt;
    cvt.h2 = h;
    return cvt.u;
}

// Max over the 16 lanes of each DPP row via rotate-and-max doubling.
// VALU pipe (v_mov_b32_dpp), NOT the DS pipe — replaces ds_swizzle shuffles.
// Verified correct in R5 (absmax 0.0).
__device__ __forceinline__ float rowmax16(float v) {
    int x;
    x = __builtin_amdgcn_update_dpp(0, __float_as_int(v), 0x121, 0xf, 0xf, true); // row_ror:1
    v = fmaxf(v, __int_as_float(x));
    x = __builtin_amdgcn_update_dpp(0, __float_as_int(v), 0x122, 0xf, 0xf, true); // row_ror:2
    v = fmaxf(v, __int_as_float(x));
    x = __builtin_amdgcn_update_dpp(0, __float_as_int(v), 0x124, 0xf, 0xf, true); // row_ror:4
    v = fmaxf(v, __int_as_float(x));
    x = __builtin_amdgcn_update_dpp(0, __float_as_int(v), 0x128, 0xf, 0xf, true); // row_ror:8
    v = fmaxf(v, __int_as_float(x));
    return v;
}

// ---------------- fp32 -> bf16 convert ----------------
__global__ void convert_kernel(const float* __restrict__ Q,
                               const float* __restrict__ K,
                               unsigned short* __restrict__ Qb,
                               unsigned short* __restrict__ Kb) {
    const int t = blockIdx.x * blockDim.x + threadIdx.x;
    const int NV4 = (PB * PL * PH) / 4;   // 262144 float4 per tensor
    const float4* src;
    unsigned short* dst;
    int i;
    if (t < NV4) { src = (const float4*)Q; dst = Qb; i = t; }
    else         { src = (const float4*)K; dst = Kb; i = t - NV4; }
    float4 v = src[i];
    uint2 o;
    o.x = pkbf(v.x, v.y);
    o.y = pkbf(v.z, v.w);
    *(uint2*)(dst + (size_t)i * 4) = o;
}

// ---------------- main scores kernel: one block per (b,c) ----------------
// R2 structure (4 row-tiles/wave, no spill) + R3 bias-folded kmask (C-operand)
// + R5 DPP epilogue (VALU-pipe reductions).
__global__ __launch_bounds__(256, 4)
void colbert_scores_mfma(const unsigned short* __restrict__ Qb,
                         const unsigned short* __restrict__ Kb,
                         const int*   __restrict__ qmask,
                         const int*   __restrict__ kmask,
                         float*       __restrict__ scores) {
    const int c = blockIdx.x;
    const int b = blockIdx.y;
    const int tid  = threadIdx.x;
    const int wave = tid >> 6;
    const int lane = tid & 63;
    const int n    = lane & 15;        // col / row-within-tile index
    const int g    = (lane >> 4) & 3;  // quad index

    __shared__ __align__(16) unsigned short Ks[PL * KSTRIDE];  // 36 KB
    __shared__ __align__(16) float qmF[PL];
    __shared__ float red4[4];

    // Issue this wave's A-fragment loads first (Qb bf16, L2-hot, 8x16B).
    // Wave handles q rows [wave*64, wave*64+64).
    const int qw0 = wave * 64;
    short8 afrag[4][2];
    {
        const unsigned short* Qrow = Qb + (size_t)b * PL * PH;
        #pragma unroll
        for (int rt = 0; rt < 4; ++rt) {
            const unsigned short* p = Qrow + (size_t)(qw0 + rt * 16 + n) * PH + g * 8;
            afrag[rt][0] = *(const short8*)(p);
            afrag[rt][1] = *(const short8*)(p + 32);
        }
    }

    // Key-mask bias per col-tile (global, 1 KB, L2-hot; issued early).
    float biasv[16];
    #pragma unroll
    for (int ct = 0; ct < 16; ++ct)
        biasv[ct] = kmask[c * PL + ct * 16 + n] ? 0.0f : NEG_INF_F;

    // Stage qmask as float.
    qmF[tid] = (float)qmask[b * PL + tid];

    // Stage K_c (256 x 64 bf16) into LDS, padded stride.
    {
        const unsigned short* Kbase = Kb + (size_t)c * PL * PH;
        #pragma unroll
        for (int it = 0; it < 8; ++it) {
            int lin = it * 256 + tid;          // 16B chunk index, 2048 total
            int row = lin >> 3;
            int off = lin & 7;
            short8 v = *(const short8*)(Kbase + (size_t)row * PH + off * 8);
            *(short8*)(&Ks[row * KSTRIDE + off * 8]) = v;
        }
    }

    __syncthreads();   // Ks + qmF visible

    // Running masked max per (rt, r); mask folded into MFMA C-init.
    float maxv[4][4];
    #pragma unroll
    for (int rt = 0; rt < 4; ++rt)
        #pragma unroll
        for (int r = 0; r < 4; ++r) maxv[rt][r] = NEG_INF_F;

    const unsigned short* krow0 = &Ks[n * KSTRIDE + g * 8];
    #pragma unroll
    for (int ct = 0; ct < 16; ++ct) {
        short8 kb0 = *(const short8*)(krow0 + ct * 16 * KSTRIDE);
        short8 kb1 = *(const short8*)(krow0 + ct * 16 * KSTRIDE + 32);
        const float bias = biasv[ct];
        const f32x4 bias4 = {bias, bias, bias, bias};

        f32x4 acc[4];
        #pragma unroll
        for (int rt = 0; rt < 4; ++rt)
            acc[rt] = __builtin_amdgcn_mfma_f32_16x16x32_bf16(afrag[rt][0], kb0, bias4, 0, 0, 0);
        #pragma unroll
        for (int rt = 0; rt < 4; ++rt)
            acc[rt] = __builtin_amdgcn_mfma_f32_16x16x32_bf16(afrag[rt][1], kb1, acc[rt], 0, 0, 0);

        #pragma unroll
        for (int rt = 0; rt < 4; ++rt)
            #pragma unroll
            for (int r = 0; r < 4; ++r)
                maxv[rt][r] = fmaxf(maxv[rt][r], acc[rt][r]);
    }

    // Col-max across the 16 lanes of each row — DPP (VALU pipe).
    // After this every lane holds its row's max.
    #pragma unroll
    for (int rt = 0; rt < 4; ++rt)
        #pragma unroll
        for (int r = 0; r < 4; ++r)
            maxv[rt][r] = rowmax16(maxv[rt][r]);

    // qmask-weighted partial; count each row once (n==0 lanes, vectorized qm read).
    float partial = 0.0f;
    if (n == 0) {
        #pragma unroll
        for (int rt = 0; rt < 4; ++rt) {
            f32x4 qm4 = *(const f32x4*)(&qmF[qw0 + rt * 16 + g * 4]);
            #pragma unroll
            for (int r = 0; r < 4; ++r)
                partial += maxv[rt][r] * qm4[r];
        }
    }
    partial += __shfl_xor(partial, 16, 64);
    partial += __shfl_xor(partial, 32, 64);
    if (lane == 0) red4[wave] = partial;
    __syncthreads();
    if (tid == 0)
        scores[b * PB + c] = (red4[0] + red4[1] + red4[2] + red4[3]) * (1.0f / TEMP);
}

// ---------------- finalize: log-softmax CE ----------------
__global__ void finalize_kernel(const float* __restrict__ scores,
                                const int*   __restrict__ labels,
                                float*       __restrict__ out) {
    const int r = threadIdx.x;   // 64 threads, one per row
    float4 v[16];
    const float4* row4 = (const float4*)(scores + r * PB);
    #pragma unroll
    for (int i = 0; i < 16; ++i) v[i] = row4[i];
    float mx = NEG_INF_F;
    #pragma unroll
    for (int i = 0; i < 16; ++i)
        mx = fmaxf(mx, fmaxf(fmaxf(v[i].x, v[i].y), fmaxf(v[i].z, v[i].w)));
    float se = 0.0f;
    #pragma unroll
    for (int i = 0; i < 16; ++i)
        se += expf(v[i].x - mx) + expf(v[i].y - mx) +
              expf(v[i].z - mx) + expf(v[i].w - mx);
    float diag = ((const float*)v)[r & 63];
    float logp_diag = diag - mx - logf(se);
    float w = (float)labels[r];
    float wd = w * logp_diag;
    #pragma unroll
    for (int off = 32; off >= 1; off >>= 1) {
        wd += __shfl_xor(wd, off, 64);
        w  += __shfl_xor(w,  off, 64);
    }
    if (r == 0) out[0] = -wd / fmaxf(w, 1.0f);
}

extern "C" void kernel_launch(void* const* d_in, const int* in_sizes, int n_in,
                              void* d_out, int out_size, void* d_ws, size_t ws_size,
                              hipStream_t stream) {
    const float* Q      = (const float*)d_in[0];
    const float* K      = (const float*)d_in[1];
    const int*   labels = (const int*)d_in[2];
    const int*   qmask  = (const int*)d_in[3];
    const int*   kmask  = (const int*)d_in[4];
    float*       out    = (float*)d_out;

    // ws layout: [scores 16KB][Qb 2MB][Kb 2MB]
    char* ws = (char*)d_ws;
    float*          scores = (float*)ws;
    unsigned short* Qb     = (unsigned short*)(ws + 16 * 1024);
    unsigned short* Kb     = (unsigned short*)(ws + 16 * 1024 + 2 * 1024 * 1024);

    const int total_v4 = 2 * (PB * PL * PH) / 4;   // 524288
    convert_kernel<<<total_v4 / 256, 256, 0, stream>>>(Q, K, Qb, Kb);

    dim3 grid(PB, PB);   // x = c, y = b; one block per (b,c), no atomics
    colbert_scores_mfma<<<grid, 256, 0, stream>>>(Qb, Kb, qmask, kmask, scores);
    finalize_kernel<<<1, 64, 0, stream>>>(scores, labels, out);
}